// Round 9
// baseline (135.757 us; speedup 1.0000x reference)
//
#include <hip/hip_runtime.h>
#include <hip/hip_bf16.h>
#include <math.h>

#define NROWS 4096
#define DIM   512
#define MAXP  128
#define TAU_INV 10.0f
#define TOT   528          // triangular tiles (32*33/2)
#define FINB  64           // fin chunks
#define FIN_START (TOT - FINB)

using short8 = __attribute__((ext_vector_type(8))) short;
using f32x4  = __attribute__((ext_vector_type(4))) float;

// ---- workspace layout (bytes) ----
#define OFF_FNB   0
#define OFF_NEG   4194304
#define OFF_RANK  (OFF_NEG  + 16384)
#define OFF_CARD  (OFF_RANK + 16384)
#define OFF_DONE  (OFF_CARD + 16384)   // done, done2, (pad)
#define OFF_PN    (OFF_DONE + 256)
#define OFF_PD    (OFF_PN   + 256)
#define OFF_PV    (OFF_PD   + 256)

#define GLOBAL_AS __attribute__((address_space(1)))
#define LDS_AS    __attribute__((address_space(3)))

__device__ __forceinline__ void gload_lds16(const void* g, void* l) {
    __builtin_amdgcn_global_load_lds((const GLOBAL_AS unsigned int*)g,
                                     (LDS_AS unsigned int*)l, 16, 0, 0);
}

__device__ __forceinline__ unsigned short f32_to_bf16_rn(float x) {
    unsigned int u = __float_as_uint(x);
    unsigned int r = u + 0x7FFFu + ((u >> 16) & 1u);
    return (unsigned short)(r >> 16);
}

// prep: one wave per row: fp32 norm -> bf16, plus deterministic rank/card
// (wave scan of tgt — no atomics, no pre-zeroed hist). Blocks 0..3 zero
// negsum; block 4 zeroes done/done2.
__global__ void k_prep(const float* __restrict__ feat, const int* __restrict__ tgt,
                       unsigned short* __restrict__ fnb,
                       int* __restrict__ rank, int* __restrict__ card,
                       float* __restrict__ negsum, int* __restrict__ done) {
    int tid = threadIdx.x;
    if (blockIdx.x < 4) ((float4*)negsum)[blockIdx.x * 256 + tid] = make_float4(0.f,0.f,0.f,0.f);
    if (blockIdx.x == 4 && tid < 2) done[tid] = 0;
    int w = tid >> 6, l = tid & 63;
    int row = blockIdx.x * 4 + w;
    // rank/card: scan all 4096 targets
    int myc = tgt[row];
    int call = 0, clt = 0;
    for (int it = 0; it < 64; it++) {
        int j = it * 64 + l;
        int t = tgt[j];
        call += (t == myc);
        clt  += (t == myc && j < row) ? 1 : 0;
    }
    #pragma unroll
    for (int m = 1; m < 64; m <<= 1) {
        call += __shfl_xor(call, m);
        clt  += __shfl_xor(clt, m);
    }
    if (l == 0) { card[row] = call; rank[row] = clt; }
    // norm
    const float4* src = (const float4*)(feat + (size_t)row * DIM);
    float4 v0 = src[l * 2];
    float4 v1 = src[l * 2 + 1];
    float ss = v0.x*v0.x + v0.y*v0.y + v0.z*v0.z + v0.w*v0.w
             + v1.x*v1.x + v1.y*v1.y + v1.z*v1.z + v1.w*v1.w;
    #pragma unroll
    for (int m = 1; m < 64; m <<= 1) ss += __shfl_xor(ss, m);
    float rs = rsqrtf(fmaxf(ss, 1e-30f));
    float f[8] = { v0.x*rs, v0.y*rs, v0.z*rs, v0.w*rs,
                   v1.x*rs, v1.y*rs, v1.z*rs, v1.w*rs };
    uint4 o;
    o.x = (unsigned)f32_to_bf16_rn(f[0]) | ((unsigned)f32_to_bf16_rn(f[1]) << 16);
    o.y = (unsigned)f32_to_bf16_rn(f[2]) | ((unsigned)f32_to_bf16_rn(f[3]) << 16);
    o.z = (unsigned)f32_to_bf16_rn(f[4]) | ((unsigned)f32_to_bf16_rn(f[5]) << 16);
    o.w = (unsigned)f32_to_bf16_rn(f[6]) | ((unsigned)f32_to_bf16_rn(f[7]) << 16);
    ((uint4*)fnb)[row * 64 + l] = o;
}

// main+fin: triangular 128x128 MFMA tiles (r7 structure, no returning atomics
// in the hot path), then done-ticket; the last 64 tickets spin until all 528
// blocks are done and run the fin chunks (no cooperative launch needed).
__global__ __launch_bounds__(256, 4)
void k_mainfin(const unsigned short* __restrict__ fnb, const int* __restrict__ tgt,
               const int* __restrict__ rank, const int* __restrict__ card,
               float* __restrict__ negsum, float* __restrict__ posvals,
               int* __restrict__ done,
               float* __restrict__ partialN, float* __restrict__ partialD,
               float* __restrict__ out)
{
    __shared__ uint4 As4[1024];
    __shared__ uint4 Bs4[1024];
    __shared__ int clsI[128], clsJ[128];
    __shared__ int rkI[128],  rkJ[128];
    __shared__ int sd;
    __shared__ float redN[4], redD[4];
    __shared__ int lastflag;

    int tid = threadIdx.x, w = tid >> 6, l = tid & 63;

    // triangular decode: b -> (bi, bj), bi <= bj
    int b = blockIdx.x;
    int bi = 0, rem = b;
    while (rem >= 32 - bi) { rem -= 32 - bi; bi++; }
    int bj = bi + rem;
    bool diag = (bi == bj);
    int i0 = bi * 128, j0 = bj * 128;

    if (tid < 128) { clsI[tid] = tgt[i0 + tid];             rkI[tid] = rank[i0 + tid]; }
    else           { clsJ[tid-128] = tgt[j0 + tid-128];     rkJ[tid-128] = rank[j0 + tid-128]; }

    int wr = w >> 1, wc = w & 1;

    f32x4 acc[4][4];
    #pragma unroll
    for (int a = 0; a < 4; a++)
        #pragma unroll
        for (int bq = 0; bq < 4; bq++)
            acc[a][bq] = (f32x4){0.f, 0.f, 0.f, 0.f};

    const uint4* gA = (const uint4*)fnb;
    const uint4* Bbase = diag ? As4 : Bs4;

    // m97 staging: source-side XOR swizzle (involution), linear LDS dest.
    for (int kt = 0; kt < 8; kt++) {
        #pragma unroll
        for (int p = 0; p < 4; p++) {
            int id = p * 256 + tid;
            int row = id >> 3, cx = id & 7;
            int c = cx ^ (row & 7);
            gload_lds16(&gA[(i0 + row) * 64 + kt * 8 + c], &As4[id]);
            if (!diag)
                gload_lds16(&gA[(j0 + row) * 64 + kt * 8 + c], &Bs4[id]);
        }
        __syncthreads();
        #pragma unroll
        for (int s = 0; s < 2; s++) {
            short8 af[4], bf[4];
            #pragma unroll
            for (int mi = 0; mi < 4; mi++) {
                int row = wr * 64 + mi * 16 + (l & 15);
                int cx = (s * 4 + (l >> 4)) ^ (row & 7);
                af[mi] = *(const short8*)&As4[row * 8 + cx];
            }
            #pragma unroll
            for (int ni = 0; ni < 4; ni++) {
                int row = wc * 64 + ni * 16 + (l & 15);
                int cx = (s * 4 + (l >> 4)) ^ (row & 7);
                bf[ni] = *(const short8*)&Bbase[row * 8 + cx];
            }
            #pragma unroll
            for (int mi = 0; mi < 4; mi++)
                #pragma unroll
                for (int ni = 0; ni < 4; ni++)
                    acc[mi][ni] = __builtin_amdgcn_mfma_f32_16x16x32_bf16(
                        af[mi], bf[ni], acc[mi][ni], 0, 0, 0);
        }
        __syncthreads();
    }

    // ---- epilogue (no returning atomics) ----
    int cj[4], gj[4], rj[4];
    #pragma unroll
    for (int ni = 0; ni < 4; ni++) {
        int jl = wc * 64 + ni * 16 + (l & 15);
        cj[ni] = clsJ[jl];
        gj[ni] = j0 + jl;
        rj[ni] = rkJ[jl];
    }
    float ns[4][4];
    float cns[4] = {0.f, 0.f, 0.f, 0.f};
    #pragma unroll
    for (int mi = 0; mi < 4; mi++) {
        #pragma unroll
        for (int r = 0; r < 4; r++) {
            int il = wr * 64 + mi * 16 + ((l >> 4) << 2) + r;
            int ci = clsI[il];
            int ri = rkI[il];
            int gi = i0 + il;
            float nacc = 0.f;
            #pragma unroll
            for (int ni = 0; ni < 4; ni++) {
                float p = acc[mi][ni][r] * TAU_INV;
                float e = __expf(p);
                if (ci != cj[ni]) {
                    nacc += e;
                    cns[ni] += e;
                } else if (gi != gj[ni]) {
                    posvals[(size_t)gi * MAXP + rj[ni]] = p;
                    if (!diag)
                        posvals[(size_t)gj[ni] * MAXP + ri] = p;
                }
            }
            ns[mi][r] = nacc;
        }
    }
    #pragma unroll
    for (int mi = 0; mi < 4; mi++) {
        #pragma unroll
        for (int r = 0; r < 4; r++) {
            float v = ns[mi][r];
            v += __shfl_xor(v, 1);
            v += __shfl_xor(v, 2);
            v += __shfl_xor(v, 4);
            v += __shfl_xor(v, 8);
            if ((l & 15) == 0) {
                int il = wr * 64 + mi * 16 + ((l >> 4) << 2) + r;
                atomicAdd(&negsum[i0 + il], v);
            }
        }
    }
    if (!diag) {
        #pragma unroll
        for (int ni = 0; ni < 4; ni++) {
            float v = cns[ni];
            v += __shfl_xor(v, 16);
            v += __shfl_xor(v, 32);
            if (l < 16) atomicAdd(&negsum[gj[ni]], v);
        }
    }

    // ---- done-ticket handoff: last 64 tickets run fin chunks ----
    __threadfence();                      // release posvals/negsum stores
    __syncthreads();
    if (tid == 0) sd = atomicAdd(&done[0], 1);
    __syncthreads();
    int d = sd;
    if (d < FIN_START) return;

    int chunk = d - FIN_START;            // 0..63
    if (tid == 0) {
        while (atomicAdd(&done[0], 0) < TOT) __builtin_amdgcn_s_sleep(16);
    }
    __syncthreads();
    __threadfence();                      // acquire: see all blocks' stores

    {
        int base = (chunk * 4 + w) * 16;
        float Sv[16]; int cv[16], rv[16];
        #pragma unroll
        for (int it = 0; it < 16; it++) {
            int row = base + it;
            Sv[it] = negsum[row];
            cv[it] = card[row];
            rv[it] = rank[row];
        }
        float nacc = 0.f, dacc = 0.f;
        #pragma unroll
        for (int it = 0; it < 16; it++) {
            int row = base + it;
            const float* pv = posvals + (size_t)row * MAXP;
            float p0 = pv[l];             // unwritten slots: poison, masked
            float p1 = pv[l + 64];
            float S = Sv[it]; int cd = cv[it], rk = rv[it];
            float t0 = __logf(__expf(p0) + S) - p0;
            float t1 = __logf(__expf(p1) + S) - p1;
            float t = ((l < cd && l != rk) ? t0 : 0.f)
                    + ((l + 64 < cd && l + 64 != rk) ? t1 : 0.f);
            nacc += t / (float)cd;
            if (l == 0) dacc += (float)cd;
        }
        #pragma unroll
        for (int msk = 1; msk < 64; msk <<= 1) {
            nacc += __shfl_xor(nacc, msk);
            dacc += __shfl_xor(dacc, msk);
        }
        if (l == 0) { redN[w] = nacc; redD[w] = dacc; }
        __syncthreads();
        if (tid == 0) {
            partialN[chunk] = redN[0] + redN[1] + redN[2] + redN[3];
            partialD[chunk] = redD[0] + redD[1] + redD[2] + redD[3];
            __threadfence();
            int d2 = atomicAdd(&done[1], 1);
            lastflag = (d2 == FINB - 1) ? 1 : 0;
        }
        __syncthreads();
        if (lastflag && tid < 64) {
            __threadfence();
            float n = partialN[tid];
            float dd = partialD[tid];
            #pragma unroll
            for (int msk = 1; msk < 64; msk <<= 1) {
                n  += __shfl_xor(n, msk);
                dd += __shfl_xor(dd, msk);
            }
            if (tid == 0) out[0] = n / dd;
        }
    }
}

extern "C" void kernel_launch(void* const* d_in, const int* in_sizes, int n_in,
                              void* d_out, int out_size, void* d_ws, size_t ws_size,
                              hipStream_t stream) {
    (void)in_sizes; (void)n_in; (void)out_size; (void)ws_size;
    const float* feat = (const float*)d_in[0];
    const int*   tgt  = (const int*)d_in[1];
    float* out = (float*)d_out;
    char* ws = (char*)d_ws;

    unsigned short* fnb = (unsigned short*)(ws + OFF_FNB);
    float* negsum  = (float*)(ws + OFF_NEG);
    int*   rank    = (int*)(ws + OFF_RANK);
    int*   card    = (int*)(ws + OFF_CARD);
    int*   done    = (int*)(ws + OFF_DONE);
    float* pN      = (float*)(ws + OFF_PN);
    float* pD      = (float*)(ws + OFF_PD);
    float* posvals = (float*)(ws + OFF_PV);

    k_prep<<<dim3(1024), dim3(256), 0, stream>>>(feat, tgt, fnb, rank, card,
                                                 negsum, done);
    k_mainfin<<<dim3(TOT), dim3(256), 0, stream>>>(fnb, tgt, rank, card,
                                                   negsum, posvals, done,
                                                   pN, pD, out);
}

// Round 10
// 117.652 us; speedup vs baseline: 1.1539x; 1.1539x over previous
//
#include <hip/hip_runtime.h>
#include <hip/hip_bf16.h>
#include <math.h>

#define NROWS 4096
#define DIM   512
#define MAXP  128
#define TAU_INV 10.0f
#define TOT   528          // triangular tiles (32*33/2)

using short8 = __attribute__((ext_vector_type(8))) short;
using f32x4  = __attribute__((ext_vector_type(4))) float;

// ---- workspace layout (bytes) ----
#define OFF_FNB   0
#define OFF_NEG   4194304
#define OFF_RANK  (OFF_NEG  + 16384)
#define OFF_SMALL (OFF_RANK + 16384)
#define OFF_HIST  (OFF_SMALL)              // int[128]
#define OFF_DONE  (OFF_SMALL + 512)
#define OFF_PN    (OFF_SMALL + 768)
#define OFF_PD    (OFF_SMALL + 1024)
#define OFF_PV    (OFF_SMALL + 2048)

#define GLOBAL_AS __attribute__((address_space(1)))
#define LDS_AS    __attribute__((address_space(3)))

__device__ __forceinline__ void gload_lds16(const void* g, void* l) {
    __builtin_amdgcn_global_load_lds((const GLOBAL_AS unsigned int*)g,
                                     (LDS_AS unsigned int*)l, 16, 0, 0);
}

__device__ __forceinline__ unsigned short f32_to_bf16_rn(float x) {
    unsigned int u = __float_as_uint(x);
    unsigned int r = u + 0x7FFFu + ((u >> 16) & 1u);
    return (unsigned short)(r >> 16);
}

// one wave per row: fp32 norm -> bf16 row. Lane 0 takes class-rank ticket.
// Blocks 0..15 zero negsum. (hist/done zeroed by the memset node.)
__global__ void k_norm(const float* __restrict__ feat, const int* __restrict__ tgt,
                       unsigned short* __restrict__ fnb, int* __restrict__ hist,
                       int* __restrict__ rank, int* __restrict__ zero_base) {
    int tid = threadIdx.x;
    if (blockIdx.x < 16) zero_base[blockIdx.x * 256 + tid] = 0;
    int wid = tid >> 6, l = tid & 63;
    int row = blockIdx.x * 4 + wid;
    if (l == 0) rank[row] = atomicAdd(&hist[tgt[row]], 1);
    const float4* src = (const float4*)(feat + (size_t)row * DIM);
    float4 v0 = src[l * 2];
    float4 v1 = src[l * 2 + 1];
    float ss = v0.x*v0.x + v0.y*v0.y + v0.z*v0.z + v0.w*v0.w
             + v1.x*v1.x + v1.y*v1.y + v1.z*v1.z + v1.w*v1.w;
    #pragma unroll
    for (int m = 1; m < 64; m <<= 1) ss += __shfl_xor(ss, m);
    float rs = rsqrtf(fmaxf(ss, 1e-30f));
    float f[8] = { v0.x*rs, v0.y*rs, v0.z*rs, v0.w*rs,
                   v1.x*rs, v1.y*rs, v1.z*rs, v1.w*rs };
    uint4 o;
    o.x = (unsigned)f32_to_bf16_rn(f[0]) | ((unsigned)f32_to_bf16_rn(f[1]) << 16);
    o.y = (unsigned)f32_to_bf16_rn(f[2]) | ((unsigned)f32_to_bf16_rn(f[3]) << 16);
    o.z = (unsigned)f32_to_bf16_rn(f[4]) | ((unsigned)f32_to_bf16_rn(f[5]) << 16);
    o.w = (unsigned)f32_to_bf16_rn(f[6]) | ((unsigned)f32_to_bf16_rn(f[7]) << 16);
    ((uint4*)fnb)[row * 64 + l] = o;
}

// main: triangular 128x128 tiles, 8 waves (2x4, wave tile 64x32), 512 threads.
// Same m97 staging (source-side XOR swizzle, linear LDS dest) and 2-barrier
// schedule as r7 — re-partitioned for 2x the resident waves (grid is
// wave-starved: 528 blocks x 4 waves was only ~8 waves/CU).
__global__ __launch_bounds__(512, 4)
void k_main(const unsigned short* __restrict__ fnb, const int* __restrict__ tgt,
            const int* __restrict__ rank,
            float* __restrict__ negsum, float* __restrict__ posvals)
{
    __shared__ uint4 As4[1024];   // [row*8 + cx], chunk = 8 bf16 = 16B
    __shared__ uint4 Bs4[1024];
    __shared__ int clsI[128], clsJ[128];
    __shared__ int rkI[128],  rkJ[128];

    // triangular decode: b -> (bi, bj), bi <= bj
    int b = blockIdx.x;
    int bi = 0, rem = b;
    while (rem >= 32 - bi) { rem -= 32 - bi; bi++; }
    int bj = bi + rem;
    bool diag = (bi == bj);
    int i0 = bi * 128, j0 = bj * 128;

    int tid = threadIdx.x;
    if (tid < 128)      { clsI[tid] = tgt[i0 + tid];         rkI[tid] = rank[i0 + tid]; }
    else if (tid < 256) { int t = tid - 128;
                          clsJ[t] = tgt[j0 + t];             rkJ[t] = rank[j0 + t]; }

    int wid = tid >> 6, l = tid & 63;
    int wr = wid >> 2, wc = wid & 3;      // 2 x 4 waves; wave tile 64 x 32

    f32x4 acc[4][2];
    #pragma unroll
    for (int a = 0; a < 4; a++)
        #pragma unroll
        for (int bq = 0; bq < 2; bq++)
            acc[a][bq] = (f32x4){0.f, 0.f, 0.f, 0.f};

    const uint4* gA = (const uint4*)fnb;
    const uint4* Bbase = diag ? As4 : Bs4;

    for (int kt = 0; kt < 8; kt++) {
        // LDS slot (row,cx) <- global chunk c = cx ^ (row&7); id linear in tid
        // so the per-lane SOURCE address carries the swizzle (rule #21).
        #pragma unroll
        for (int p = 0; p < 2; p++) {
            int id = p * 512 + tid;             // 0..1023
            int row = id >> 3, cx = id & 7;
            int c = cx ^ (row & 7);
            gload_lds16(&gA[(i0 + row) * 64 + kt * 8 + c], &As4[id]);
            if (!diag)
                gload_lds16(&gA[(j0 + row) * 64 + kt * 8 + c], &Bs4[id]);
        }
        __syncthreads();
        #pragma unroll
        for (int s = 0; s < 2; s++) {
            short8 af[4], bf[2];
            #pragma unroll
            for (int mi = 0; mi < 4; mi++) {
                int row = wr * 64 + mi * 16 + (l & 15);
                int cx = (s * 4 + (l >> 4)) ^ (row & 7);
                af[mi] = *(const short8*)&As4[row * 8 + cx];
            }
            #pragma unroll
            for (int ni = 0; ni < 2; ni++) {
                int row = wc * 32 + ni * 16 + (l & 15);
                int cx = (s * 4 + (l >> 4)) ^ (row & 7);
                bf[ni] = *(const short8*)&Bbase[row * 8 + cx];
            }
            #pragma unroll
            for (int mi = 0; mi < 4; mi++)
                #pragma unroll
                for (int ni = 0; ni < 2; ni++)
                    acc[mi][ni] = __builtin_amdgcn_mfma_f32_16x16x32_bf16(
                        af[mi], bf[ni], acc[mi][ni], 0, 0, 0);
        }
        __syncthreads();
    }

    // ---- epilogue (no returning atomics) ----
    int cj[2], gj[2], rj[2];
    #pragma unroll
    for (int ni = 0; ni < 2; ni++) {
        int jl = wc * 32 + ni * 16 + (l & 15);
        cj[ni] = clsJ[jl];
        gj[ni] = j0 + jl;
        rj[ni] = rkJ[jl];
    }
    float ns[4][4];
    float cns[2] = {0.f, 0.f};
    #pragma unroll
    for (int mi = 0; mi < 4; mi++) {
        #pragma unroll
        for (int r = 0; r < 4; r++) {
            int il = wr * 64 + mi * 16 + ((l >> 4) << 2) + r;
            int ci = clsI[il];
            int ri = rkI[il];
            int gi = i0 + il;
            float nacc = 0.f;
            #pragma unroll
            for (int ni = 0; ni < 2; ni++) {
                float p = acc[mi][ni][r] * TAU_INV;
                float e = __expf(p);
                if (ci != cj[ni]) {
                    nacc += e;
                    cns[ni] += e;
                } else if (gi != gj[ni]) {
                    posvals[(size_t)gi * MAXP + rj[ni]] = p;       // slot = rank[j]
                    if (!diag)
                        posvals[(size_t)gj[ni] * MAXP + ri] = p;   // slot = rank[i]
                }
            }
            ns[mi][r] = nacc;
        }
    }
    // row-i reduce: 16-lane butterfly, non-returning atomic
    #pragma unroll
    for (int mi = 0; mi < 4; mi++) {
        #pragma unroll
        for (int r = 0; r < 4; r++) {
            float v = ns[mi][r];
            v += __shfl_xor(v, 1);
            v += __shfl_xor(v, 2);
            v += __shfl_xor(v, 4);
            v += __shfl_xor(v, 8);
            if ((l & 15) == 0) {
                int il = wr * 64 + mi * 16 + ((l >> 4) << 2) + r;
                atomicAdd(&negsum[i0 + il], v);
            }
        }
    }
    // col-j reduce (off-diag): combine the 4 row-groups of this wave's 64 rows
    if (!diag) {
        #pragma unroll
        for (int ni = 0; ni < 2; ni++) {
            float v = cns[ni];
            v += __shfl_xor(v, 16);
            v += __shfl_xor(v, 32);
            if (l < 16) atomicAdd(&negsum[gj[ni]], v);
        }
    }
}

// wave per 16 rows; card = hist[class]; per-lane accumulation; per-block
// partial stores + done-ticket finalize.
__global__ void k_fin(const float* __restrict__ negsum, const int* __restrict__ tgt,
                      const int* __restrict__ rank, const int* __restrict__ hist,
                      const float* __restrict__ posvals,
                      float* __restrict__ partialN, float* __restrict__ partialD,
                      int* __restrict__ done, float* __restrict__ out)
{
    __shared__ float redN[4], redD[4];
    __shared__ int lastflag;
    int tid = threadIdx.x, w = tid >> 6, l = tid & 63;
    int base = (blockIdx.x * 4 + w) * 16;
    float Sv[16]; int cv[16], rv[16];
    #pragma unroll
    for (int it = 0; it < 16; it++) {
        int row = base + it;
        Sv[it] = negsum[row];
        cv[it] = hist[tgt[row]];
        rv[it] = rank[row];
    }
    float nacc = 0.f, dacc = 0.f;
    #pragma unroll
    for (int it = 0; it < 16; it++) {
        int row = base + it;
        const float* pv = posvals + (size_t)row * MAXP;
        float p0 = pv[l];          // unwritten slots: harmless poison, masked
        float p1 = pv[l + 64];
        float S = Sv[it]; int card = cv[it], rk = rv[it];
        float t0 = __logf(__expf(p0) + S) - p0;
        float t1 = __logf(__expf(p1) + S) - p1;
        float t = ((l < card && l != rk) ? t0 : 0.f)
                + ((l + 64 < card && l + 64 != rk) ? t1 : 0.f);
        nacc += t / (float)card;
        if (l == 0) dacc += (float)card;
    }
    #pragma unroll
    for (int msk = 1; msk < 64; msk <<= 1) {
        nacc += __shfl_xor(nacc, msk);
        dacc += __shfl_xor(dacc, msk);
    }
    if (l == 0) { redN[w] = nacc; redD[w] = dacc; }
    __syncthreads();
    if (tid == 0) {
        partialN[blockIdx.x] = redN[0] + redN[1] + redN[2] + redN[3];
        partialD[blockIdx.x] = redD[0] + redD[1] + redD[2] + redD[3];
        __threadfence();
        int d = atomicAdd(done, 1);
        lastflag = (d == (int)gridDim.x - 1) ? 1 : 0;
    }
    __syncthreads();
    if (lastflag && tid < 64) {
        __threadfence();
        float n = partialN[tid];
        float dd = partialD[tid];
        #pragma unroll
        for (int msk = 1; msk < 64; msk <<= 1) {
            n  += __shfl_xor(n, msk);
            dd += __shfl_xor(dd, msk);
        }
        if (tid == 0) out[0] = n / dd;
    }
}

extern "C" void kernel_launch(void* const* d_in, const int* in_sizes, int n_in,
                              void* d_out, int out_size, void* d_ws, size_t ws_size,
                              hipStream_t stream) {
    (void)in_sizes; (void)n_in; (void)out_size; (void)ws_size;
    const float* feat = (const float*)d_in[0];
    const int*   tgt  = (const int*)d_in[1];
    float* out = (float*)d_out;
    char* ws = (char*)d_ws;

    unsigned short* fnb = (unsigned short*)(ws + OFF_FNB);
    float* negsum  = (float*)(ws + OFF_NEG);
    int*   rank    = (int*)(ws + OFF_RANK);
    int*   hist    = (int*)(ws + OFF_HIST);
    int*   done    = (int*)(ws + OFF_DONE);
    float* pN      = (float*)(ws + OFF_PN);
    float* pD      = (float*)(ws + OFF_PD);
    float* posvals = (float*)(ws + OFF_PV);

    // hist + done must be zero before k_norm's rank tickets
    hipMemsetAsync(ws + OFF_SMALL, 0, 768, stream);

    k_norm<<<dim3(1024), dim3(256), 0, stream>>>(feat, tgt, fnb, hist, rank,
                                                 (int*)(ws + OFF_NEG));
    k_main<<<dim3(TOT), dim3(512), 0, stream>>>(fnb, tgt, rank, negsum, posvals);
    k_fin<<<dim3(64), dim3(256), 0, stream>>>(negsum, tgt, rank, hist, posvals,
                                              pN, pD, done, out);
}

// Round 11
// 106.176 us; speedup vs baseline: 1.2786x; 1.1081x over previous
//
#include <hip/hip_runtime.h>
#include <hip/hip_bf16.h>
#include <math.h>

#define NROWS 4096
#define DIM   512
#define MAXP  128
#define TAU_INV 10.0f
#define NPAN  64                    // 4096 / 64
#define TOT   (NPAN*(NPAN+1)/2)     // 2080 triangular 64x64 tiles

using short8 = __attribute__((ext_vector_type(8))) short;
using f32x4  = __attribute__((ext_vector_type(4))) float;

// ---- workspace layout (bytes) ----
#define OFF_FNB   0
#define OFF_NEG   4194304
#define OFF_RANK  (OFF_NEG  + 16384)
#define OFF_CARD  (OFF_RANK + 16384)
#define OFF_DONE  (OFF_CARD + 16384)
#define OFF_PN    (OFF_DONE + 256)
#define OFF_PD    (OFF_PN   + 256)
#define OFF_PV    (OFF_PD   + 256)

#define GLOBAL_AS __attribute__((address_space(1)))
#define LDS_AS    __attribute__((address_space(3)))

__device__ __forceinline__ void gload_lds16(const void* g, void* l) {
    __builtin_amdgcn_global_load_lds((const GLOBAL_AS unsigned int*)g,
                                     (LDS_AS unsigned int*)l, 16, 0, 0);
}

__device__ __forceinline__ unsigned short f32_to_bf16_rn(float x) {
    unsigned int u = __float_as_uint(x);
    unsigned int r = u + 0x7FFFu + ((u >> 16) & 1u);
    return (unsigned short)(r >> 16);
}

// prep (verified r9): one wave per row: fp32 norm -> bf16, deterministic
// rank/card via wave scan of tgt (no atomics, no memset dependency).
// Blocks 0..3 zero negsum; block 4 zeroes done tickets.
__global__ void k_prep(const float* __restrict__ feat, const int* __restrict__ tgt,
                       unsigned short* __restrict__ fnb,
                       int* __restrict__ rank, int* __restrict__ card,
                       float* __restrict__ negsum, int* __restrict__ done) {
    int tid = threadIdx.x;
    if (blockIdx.x < 4) ((float4*)negsum)[blockIdx.x * 256 + tid] = make_float4(0.f,0.f,0.f,0.f);
    if (blockIdx.x == 4 && tid < 2) done[tid] = 0;
    int w = tid >> 6, l = tid & 63;
    int row = blockIdx.x * 4 + w;
    int myc = tgt[row];
    int call = 0, clt = 0;
    for (int it = 0; it < 64; it++) {
        int j = it * 64 + l;
        int t = tgt[j];
        call += (t == myc);
        clt  += (t == myc && j < row) ? 1 : 0;
    }
    #pragma unroll
    for (int m = 1; m < 64; m <<= 1) {
        call += __shfl_xor(call, m);
        clt  += __shfl_xor(clt, m);
    }
    if (l == 0) { card[row] = call; rank[row] = clt; }
    const float4* src = (const float4*)(feat + (size_t)row * DIM);
    float4 v0 = src[l * 2];
    float4 v1 = src[l * 2 + 1];
    float ss = v0.x*v0.x + v0.y*v0.y + v0.z*v0.z + v0.w*v0.w
             + v1.x*v1.x + v1.y*v1.y + v1.z*v1.z + v1.w*v1.w;
    #pragma unroll
    for (int m = 1; m < 64; m <<= 1) ss += __shfl_xor(ss, m);
    float rs = rsqrtf(fmaxf(ss, 1e-30f));
    float f[8] = { v0.x*rs, v0.y*rs, v0.z*rs, v0.w*rs,
                   v1.x*rs, v1.y*rs, v1.z*rs, v1.w*rs };
    uint4 o;
    o.x = (unsigned)f32_to_bf16_rn(f[0]) | ((unsigned)f32_to_bf16_rn(f[1]) << 16);
    o.y = (unsigned)f32_to_bf16_rn(f[2]) | ((unsigned)f32_to_bf16_rn(f[3]) << 16);
    o.z = (unsigned)f32_to_bf16_rn(f[4]) | ((unsigned)f32_to_bf16_rn(f[5]) << 16);
    o.w = (unsigned)f32_to_bf16_rn(f[6]) | ((unsigned)f32_to_bf16_rn(f[7]) << 16);
    ((uint4*)fnb)[row * 64 + l] = o;
}

// main: triangular 64x64 tiles, 2080 blocks, 4 waves (each one 32x32 subtile).
// Many small blocks -> ~24 waves/CU resident so the per-block stage/barrier
// stall overlaps across blocks (m114 mechanism). Same verified staging
// (source-side XOR swizzle involution, linear LDS dest) and epilogue math.
__global__ __launch_bounds__(256, 6)
void k_main(const unsigned short* __restrict__ fnb, const int* __restrict__ tgt,
            const int* __restrict__ rank,
            float* __restrict__ negsum, float* __restrict__ posvals)
{
    __shared__ uint4 As4[512];    // [row*8 + cx], 64 rows x 8 chunks (8 KB)
    __shared__ uint4 Bs4[512];
    __shared__ int clsI[64], clsJ[64];
    __shared__ int rkI[64],  rkJ[64];

    // triangular decode: b -> (bi, bj), bi <= bj over 64 panels
    int b = blockIdx.x;
    int bi = 0, rem = b;
    while (rem >= NPAN - bi) { rem -= NPAN - bi; bi++; }
    int bj = bi + rem;
    bool diag = (bi == bj);
    int i0 = bi * 64, j0 = bj * 64;

    int tid = threadIdx.x;
    if (tid < 64)       { clsI[tid] = tgt[i0 + tid];       rkI[tid] = rank[i0 + tid]; }
    else if (tid < 128) { int t = tid - 64;
                          clsJ[t] = tgt[j0 + t];           rkJ[t] = rank[j0 + t]; }

    int wid = tid >> 6, l = tid & 63;
    int wr = wid >> 1, wc = wid & 1;       // 2x2 waves; wave tile 32x32

    f32x4 acc[2][2];
    #pragma unroll
    for (int a = 0; a < 2; a++)
        #pragma unroll
        for (int bq = 0; bq < 2; bq++)
            acc[a][bq] = (f32x4){0.f, 0.f, 0.f, 0.f};

    const uint4* gA = (const uint4*)fnb;
    const uint4* Bbase = diag ? As4 : Bs4;

    for (int kt = 0; kt < 8; kt++) {
        // LDS slot (row,cx) <- global chunk c = cx ^ (row&7); id linear in tid
        // so the per-lane SOURCE address carries the swizzle (rule #21).
        #pragma unroll
        for (int p = 0; p < 2; p++) {
            int id = p * 256 + tid;            // 0..511
            int row = id >> 3, cx = id & 7;
            int c = cx ^ (row & 7);
            gload_lds16(&gA[(i0 + row) * 64 + kt * 8 + c], &As4[id]);
            if (!diag)
                gload_lds16(&gA[(j0 + row) * 64 + kt * 8 + c], &Bs4[id]);
        }
        __syncthreads();
        #pragma unroll
        for (int s = 0; s < 2; s++) {
            short8 af[2], bf[2];
            #pragma unroll
            for (int mi = 0; mi < 2; mi++) {
                int row = wr * 32 + mi * 16 + (l & 15);
                int cx = (s * 4 + (l >> 4)) ^ (row & 7);
                af[mi] = *(const short8*)&As4[row * 8 + cx];
            }
            #pragma unroll
            for (int ni = 0; ni < 2; ni++) {
                int row = wc * 32 + ni * 16 + (l & 15);
                int cx = (s * 4 + (l >> 4)) ^ (row & 7);
                bf[ni] = *(const short8*)&Bbase[row * 8 + cx];
            }
            #pragma unroll
            for (int mi = 0; mi < 2; mi++)
                #pragma unroll
                for (int ni = 0; ni < 2; ni++)
                    acc[mi][ni] = __builtin_amdgcn_mfma_f32_16x16x32_bf16(
                        af[mi], bf[ni], acc[mi][ni], 0, 0, 0);
        }
        __syncthreads();
    }

    // ---- epilogue (no returning atomics) ----
    int cj[2], gj[2], rj[2];
    #pragma unroll
    for (int ni = 0; ni < 2; ni++) {
        int jl = wc * 32 + ni * 16 + (l & 15);
        cj[ni] = clsJ[jl];
        gj[ni] = j0 + jl;
        rj[ni] = rkJ[jl];
    }
    float ns[2][4];
    float cns[2] = {0.f, 0.f};
    #pragma unroll
    for (int mi = 0; mi < 2; mi++) {
        #pragma unroll
        for (int r = 0; r < 4; r++) {
            int il = wr * 32 + mi * 16 + ((l >> 4) << 2) + r;
            int ci = clsI[il];
            int ri = rkI[il];
            int gi = i0 + il;
            float nacc = 0.f;
            #pragma unroll
            for (int ni = 0; ni < 2; ni++) {
                float p = acc[mi][ni][r] * TAU_INV;
                float e = __expf(p);
                if (ci != cj[ni]) {
                    nacc += e;
                    cns[ni] += e;
                } else if (gi != gj[ni]) {
                    posvals[(size_t)gi * MAXP + rj[ni]] = p;       // slot = rank[j]
                    if (!diag)
                        posvals[(size_t)gj[ni] * MAXP + ri] = p;   // slot = rank[i]
                }
            }
            ns[mi][r] = nacc;
        }
    }
    // row-i reduce: 16-lane butterfly (cols), non-returning atomic
    #pragma unroll
    for (int mi = 0; mi < 2; mi++) {
        #pragma unroll
        for (int r = 0; r < 4; r++) {
            float v = ns[mi][r];
            v += __shfl_xor(v, 1);
            v += __shfl_xor(v, 2);
            v += __shfl_xor(v, 4);
            v += __shfl_xor(v, 8);
            if ((l & 15) == 0) {
                int il = wr * 32 + mi * 16 + ((l >> 4) << 2) + r;
                atomicAdd(&negsum[i0 + il], v);
            }
        }
    }
    // col-j reduce (off-diag): sum over the 4 row-groups
    if (!diag) {
        #pragma unroll
        for (int ni = 0; ni < 2; ni++) {
            float v = cns[ni];
            v += __shfl_xor(v, 16);
            v += __shfl_xor(v, 32);
            if (l < 16) atomicAdd(&negsum[gj[ni]], v);
        }
    }
}

// wave per 16 rows; card from card[]; per-lane accumulation; per-block
// partial stores + done-ticket finalize.
__global__ void k_fin(const float* __restrict__ negsum,
                      const int* __restrict__ rank, const int* __restrict__ card,
                      const float* __restrict__ posvals,
                      float* __restrict__ partialN, float* __restrict__ partialD,
                      int* __restrict__ done, float* __restrict__ out)
{
    __shared__ float redN[4], redD[4];
    __shared__ int lastflag;
    int tid = threadIdx.x, w = tid >> 6, l = tid & 63;
    int base = (blockIdx.x * 4 + w) * 16;
    float Sv[16]; int cv[16], rv[16];
    #pragma unroll
    for (int it = 0; it < 16; it++) {
        int row = base + it;
        Sv[it] = negsum[row];
        cv[it] = card[row];
        rv[it] = rank[row];
    }
    float nacc = 0.f, dacc = 0.f;
    #pragma unroll
    for (int it = 0; it < 16; it++) {
        int row = base + it;
        const float* pv = posvals + (size_t)row * MAXP;
        float p0 = pv[l];          // unwritten slots: harmless poison, masked
        float p1 = pv[l + 64];
        float S = Sv[it]; int cd = cv[it], rk = rv[it];
        float t0 = __logf(__expf(p0) + S) - p0;
        float t1 = __logf(__expf(p1) + S) - p1;
        float t = ((l < cd && l != rk) ? t0 : 0.f)
                + ((l + 64 < cd && l + 64 != rk) ? t1 : 0.f);
        nacc += t / (float)cd;
        if (l == 0) dacc += (float)cd;
    }
    #pragma unroll
    for (int msk = 1; msk < 64; msk <<= 1) {
        nacc += __shfl_xor(nacc, msk);
        dacc += __shfl_xor(dacc, msk);
    }
    if (l == 0) { redN[w] = nacc; redD[w] = dacc; }
    __syncthreads();
    if (tid == 0) {
        partialN[blockIdx.x] = redN[0] + redN[1] + redN[2] + redN[3];
        partialD[blockIdx.x] = redD[0] + redD[1] + redD[2] + redD[3];
        __threadfence();
        int d = atomicAdd(done, 1);
        lastflag = (d == (int)gridDim.x - 1) ? 1 : 0;
    }
    __syncthreads();
    if (lastflag && tid < 64) {
        __threadfence();
        float n = partialN[tid];
        float dd = partialD[tid];
        #pragma unroll
        for (int msk = 1; msk < 64; msk <<= 1) {
            n  += __shfl_xor(n, msk);
            dd += __shfl_xor(dd, msk);
        }
        if (tid == 0) out[0] = n / dd;
    }
}

extern "C" void kernel_launch(void* const* d_in, const int* in_sizes, int n_in,
                              void* d_out, int out_size, void* d_ws, size_t ws_size,
                              hipStream_t stream) {
    (void)in_sizes; (void)n_in; (void)out_size; (void)ws_size;
    const float* feat = (const float*)d_in[0];
    const int*   tgt  = (const int*)d_in[1];
    float* out = (float*)d_out;
    char* ws = (char*)d_ws;

    unsigned short* fnb = (unsigned short*)(ws + OFF_FNB);
    float* negsum  = (float*)(ws + OFF_NEG);
    int*   rank    = (int*)(ws + OFF_RANK);
    int*   card    = (int*)(ws + OFF_CARD);
    int*   done    = (int*)(ws + OFF_DONE);
    float* pN      = (float*)(ws + OFF_PN);
    float* pD      = (float*)(ws + OFF_PD);
    float* posvals = (float*)(ws + OFF_PV);

    k_prep<<<dim3(1024), dim3(256), 0, stream>>>(feat, tgt, fnb, rank, card,
                                                 negsum, done);
    k_main<<<dim3(TOT), dim3(256), 0, stream>>>(fnb, tgt, rank, negsum, posvals);
    k_fin<<<dim3(64), dim3(256), 0, stream>>>(negsum, rank, card, posvals,
                                              pN, pD, done, out);
}

// Round 12
// 94.194 us; speedup vs baseline: 1.4412x; 1.1272x over previous
//
#include <hip/hip_runtime.h>
#include <hip/hip_bf16.h>
#include <math.h>

#define NROWS 4096
#define DIM   512
#define MAXP  128
#define TAU_INV 10.0f
#define NPAN  32                    // 4096 / 128
#define TOT   (NPAN*(NPAN+1)/2)     // 528 triangular 128x128 tiles
#define CPX   (TOT/8)               // 66 tiles per XCD (528 = 8*66, bijective)

using short8 = __attribute__((ext_vector_type(8))) short;
using f32x4  = __attribute__((ext_vector_type(4))) float;

// ---- workspace layout (bytes) ----
#define OFF_FNB   0
#define OFF_NEG   4194304
#define OFF_RANK  (OFF_NEG  + 16384)
#define OFF_CARD  (OFF_RANK + 16384)
#define OFF_DONE  (OFF_CARD + 16384)
#define OFF_PN    (OFF_DONE + 256)
#define OFF_PD    (OFF_PN   + 256)
#define OFF_PV    (OFF_PD   + 256)

#define GLOBAL_AS __attribute__((address_space(1)))
#define LDS_AS    __attribute__((address_space(3)))

__device__ __forceinline__ void gload_lds16(const void* g, void* l) {
    __builtin_amdgcn_global_load_lds((const GLOBAL_AS unsigned int*)g,
                                     (LDS_AS unsigned int*)l, 16, 0, 0);
}

__device__ __forceinline__ unsigned short f32_to_bf16_rn(float x) {
    unsigned int u = __float_as_uint(x);
    unsigned int r = u + 0x7FFFu + ((u >> 16) & 1u);
    return (unsigned short)(r >> 16);
}

// prep (verified r9/r11): one wave per row: fp32 norm -> bf16, deterministic
// rank/card via wave scan of tgt. Blocks 0..3 zero negsum; block 4 zeroes done.
__global__ void k_prep(const float* __restrict__ feat, const int* __restrict__ tgt,
                       unsigned short* __restrict__ fnb,
                       int* __restrict__ rank, int* __restrict__ card,
                       float* __restrict__ negsum, int* __restrict__ done) {
    int tid = threadIdx.x;
    if (blockIdx.x < 4) ((float4*)negsum)[blockIdx.x * 256 + tid] = make_float4(0.f,0.f,0.f,0.f);
    if (blockIdx.x == 4 && tid < 2) done[tid] = 0;
    int w = tid >> 6, l = tid & 63;
    int row = blockIdx.x * 4 + w;
    int myc = tgt[row];
    int call = 0, clt = 0;
    for (int it = 0; it < 64; it++) {
        int j = it * 64 + l;
        int t = tgt[j];
        call += (t == myc);
        clt  += (t == myc && j < row) ? 1 : 0;
    }
    #pragma unroll
    for (int m = 1; m < 64; m <<= 1) {
        call += __shfl_xor(call, m);
        clt  += __shfl_xor(clt, m);
    }
    if (l == 0) { card[row] = call; rank[row] = clt; }
    const float4* src = (const float4*)(feat + (size_t)row * DIM);
    float4 v0 = src[l * 2];
    float4 v1 = src[l * 2 + 1];
    float ss = v0.x*v0.x + v0.y*v0.y + v0.z*v0.z + v0.w*v0.w
             + v1.x*v1.x + v1.y*v1.y + v1.z*v1.z + v1.w*v1.w;
    #pragma unroll
    for (int m = 1; m < 64; m <<= 1) ss += __shfl_xor(ss, m);
    float rs = rsqrtf(fmaxf(ss, 1e-30f));
    float f[8] = { v0.x*rs, v0.y*rs, v0.z*rs, v0.w*rs,
                   v1.x*rs, v1.y*rs, v1.z*rs, v1.w*rs };
    uint4 o;
    o.x = (unsigned)f32_to_bf16_rn(f[0]) | ((unsigned)f32_to_bf16_rn(f[1]) << 16);
    o.y = (unsigned)f32_to_bf16_rn(f[2]) | ((unsigned)f32_to_bf16_rn(f[3]) << 16);
    o.z = (unsigned)f32_to_bf16_rn(f[4]) | ((unsigned)f32_to_bf16_rn(f[5]) << 16);
    o.w = (unsigned)f32_to_bf16_rn(f[6]) | ((unsigned)f32_to_bf16_rn(f[7]) << 16);
    ((uint4*)fnb)[row * 64 + l] = o;
}

// main: r7 structure (triangular 128x128, 4 waves 2x2, m97 staging, no
// returning atomics) + chunked XCD swizzle: tile = (bid%8)*66 + bid/8, so
// each XCD owns a contiguous bi-band -> panel working set ~4.4MB fits its
// private L2 instead of thrashing ~8MB across L3/fabric (the invariant
// ~45us staging bound seen r4/r6/r7/r11).
__global__ __launch_bounds__(256, 4)
void k_main(const unsigned short* __restrict__ fnb, const int* __restrict__ tgt,
            const int* __restrict__ rank,
            float* __restrict__ negsum, float* __restrict__ posvals)
{
    __shared__ uint4 As4[1024];   // [row*8 + cx], chunk = 8 bf16 = 16B
    __shared__ uint4 Bs4[1024];
    __shared__ int clsI[128], clsJ[128];
    __shared__ int rkI[128],  rkJ[128];

    // XCD-chunked bijective swizzle (528 = 8 * 66)
    int bid = blockIdx.x;
    int b = (bid & 7) * CPX + (bid >> 3);

    // triangular decode: b -> (bi, bj), bi <= bj
    int bi = 0, rem = b;
    while (rem >= NPAN - bi) { rem -= NPAN - bi; bi++; }
    int bj = bi + rem;
    bool diag = (bi == bj);
    int i0 = bi * 128, j0 = bj * 128;

    int tid = threadIdx.x;
    if (tid < 128) { clsI[tid] = tgt[i0 + tid];             rkI[tid] = rank[i0 + tid]; }
    else           { clsJ[tid-128] = tgt[j0 + tid-128];     rkJ[tid-128] = rank[j0 + tid-128]; }

    int wid = tid >> 6, l = tid & 63;
    int wr = wid >> 1, wc = wid & 1;

    f32x4 acc[4][4];
    #pragma unroll
    for (int a = 0; a < 4; a++)
        #pragma unroll
        for (int bq = 0; bq < 4; bq++)
            acc[a][bq] = (f32x4){0.f, 0.f, 0.f, 0.f};

    const uint4* gA = (const uint4*)fnb;
    const uint4* Bbase = diag ? As4 : Bs4;

    for (int kt = 0; kt < 8; kt++) {
        // LDS slot (row,cx) <- global chunk c = cx ^ (row&7); id linear in tid
        // so the per-lane SOURCE address carries the swizzle (rule #21).
        #pragma unroll
        for (int p = 0; p < 4; p++) {
            int id = p * 256 + tid;
            int row = id >> 3, cx = id & 7;
            int c = cx ^ (row & 7);
            gload_lds16(&gA[(i0 + row) * 64 + kt * 8 + c], &As4[id]);
            if (!diag)
                gload_lds16(&gA[(j0 + row) * 64 + kt * 8 + c], &Bs4[id]);
        }
        __syncthreads();
        #pragma unroll
        for (int s = 0; s < 2; s++) {
            short8 af[4], bf[4];
            #pragma unroll
            for (int mi = 0; mi < 4; mi++) {
                int row = wr * 64 + mi * 16 + (l & 15);
                int cx = (s * 4 + (l >> 4)) ^ (row & 7);
                af[mi] = *(const short8*)&As4[row * 8 + cx];
            }
            #pragma unroll
            for (int ni = 0; ni < 4; ni++) {
                int row = wc * 64 + ni * 16 + (l & 15);
                int cx = (s * 4 + (l >> 4)) ^ (row & 7);
                bf[ni] = *(const short8*)&Bbase[row * 8 + cx];
            }
            #pragma unroll
            for (int mi = 0; mi < 4; mi++)
                #pragma unroll
                for (int ni = 0; ni < 4; ni++)
                    acc[mi][ni] = __builtin_amdgcn_mfma_f32_16x16x32_bf16(
                        af[mi], bf[ni], acc[mi][ni], 0, 0, 0);
        }
        __syncthreads();
    }

    // ---- epilogue (no returning atomics) ----
    int cj[4], gj[4], rj[4];
    #pragma unroll
    for (int ni = 0; ni < 4; ni++) {
        int jl = wc * 64 + ni * 16 + (l & 15);
        cj[ni] = clsJ[jl];
        gj[ni] = j0 + jl;
        rj[ni] = rkJ[jl];
    }
    float ns[4][4];
    float cns[4] = {0.f, 0.f, 0.f, 0.f};
    #pragma unroll
    for (int mi = 0; mi < 4; mi++) {
        #pragma unroll
        for (int r = 0; r < 4; r++) {
            int il = wr * 64 + mi * 16 + ((l >> 4) << 2) + r;
            int ci = clsI[il];
            int ri = rkI[il];
            int gi = i0 + il;
            float nacc = 0.f;
            #pragma unroll
            for (int ni = 0; ni < 4; ni++) {
                float p = acc[mi][ni][r] * TAU_INV;
                float e = __expf(p);
                if (ci != cj[ni]) {
                    nacc += e;
                    cns[ni] += e;
                } else if (gi != gj[ni]) {
                    posvals[(size_t)gi * MAXP + rj[ni]] = p;       // slot = rank[j]
                    if (!diag)
                        posvals[(size_t)gj[ni] * MAXP + ri] = p;   // slot = rank[i]
                }
            }
            ns[mi][r] = nacc;
        }
    }
    // row-i reduce: 16-lane butterfly, non-returning atomic
    #pragma unroll
    for (int mi = 0; mi < 4; mi++) {
        #pragma unroll
        for (int r = 0; r < 4; r++) {
            float v = ns[mi][r];
            v += __shfl_xor(v, 1);
            v += __shfl_xor(v, 2);
            v += __shfl_xor(v, 4);
            v += __shfl_xor(v, 8);
            if ((l & 15) == 0) {
                int il = wr * 64 + mi * 16 + ((l >> 4) << 2) + r;
                atomicAdd(&negsum[i0 + il], v);
            }
        }
    }
    // col-j reduce (off-diag): sum over the 4 row-groups
    if (!diag) {
        #pragma unroll
        for (int ni = 0; ni < 4; ni++) {
            float v = cns[ni];
            v += __shfl_xor(v, 16);
            v += __shfl_xor(v, 32);
            if (l < 16) atomicAdd(&negsum[gj[ni]], v);
        }
    }
}

// wave per 16 rows; card from card[]; per-lane accumulation; per-block
// partial stores + done-ticket finalize.
__global__ void k_fin(const float* __restrict__ negsum,
                      const int* __restrict__ rank, const int* __restrict__ card,
                      const float* __restrict__ posvals,
                      float* __restrict__ partialN, float* __restrict__ partialD,
                      int* __restrict__ done, float* __restrict__ out)
{
    __shared__ float redN[4], redD[4];
    __shared__ int lastflag;
    int tid = threadIdx.x, w = tid >> 6, l = tid & 63;
    int base = (blockIdx.x * 4 + w) * 16;
    float Sv[16]; int cv[16], rv[16];
    #pragma unroll
    for (int it = 0; it < 16; it++) {
        int row = base + it;
        Sv[it] = negsum[row];
        cv[it] = card[row];
        rv[it] = rank[row];
    }
    float nacc = 0.f, dacc = 0.f;
    #pragma unroll
    for (int it = 0; it < 16; it++) {
        int row = base + it;
        const float* pv = posvals + (size_t)row * MAXP;
        float p0 = pv[l];          // unwritten slots: harmless poison, masked
        float p1 = pv[l + 64];
        float S = Sv[it]; int cd = cv[it], rk = rv[it];
        float t0 = __logf(__expf(p0) + S) - p0;
        float t1 = __logf(__expf(p1) + S) - p1;
        float t = ((l < cd && l != rk) ? t0 : 0.f)
                + ((l + 64 < cd && l + 64 != rk) ? t1 : 0.f);
        nacc += t / (float)cd;
        if (l == 0) dacc += (float)cd;
    }
    #pragma unroll
    for (int msk = 1; msk < 64; msk <<= 1) {
        nacc += __shfl_xor(nacc, msk);
        dacc += __shfl_xor(dacc, msk);
    }
    if (l == 0) { redN[w] = nacc; redD[w] = dacc; }
    __syncthreads();
    if (tid == 0) {
        partialN[blockIdx.x] = redN[0] + redN[1] + redN[2] + redN[3];
        partialD[blockIdx.x] = redD[0] + redD[1] + redD[2] + redD[3];
        __threadfence();
        int d = atomicAdd(done, 1);
        lastflag = (d == (int)gridDim.x - 1) ? 1 : 0;
    }
    __syncthreads();
    if (lastflag && tid < 64) {
        __threadfence();
        float n = partialN[tid];
        float dd = partialD[tid];
        #pragma unroll
        for (int msk = 1; msk < 64; msk <<= 1) {
            n  += __shfl_xor(n, msk);
            dd += __shfl_xor(dd, msk);
        }
        if (tid == 0) out[0] = n / dd;
    }
}

extern "C" void kernel_launch(void* const* d_in, const int* in_sizes, int n_in,
                              void* d_out, int out_size, void* d_ws, size_t ws_size,
                              hipStream_t stream) {
    (void)in_sizes; (void)n_in; (void)out_size; (void)ws_size;
    const float* feat = (const float*)d_in[0];
    const int*   tgt  = (const int*)d_in[1];
    float* out = (float*)d_out;
    char* ws = (char*)d_ws;

    unsigned short* fnb = (unsigned short*)(ws + OFF_FNB);
    float* negsum  = (float*)(ws + OFF_NEG);
    int*   rank    = (int*)(ws + OFF_RANK);
    int*   card    = (int*)(ws + OFF_CARD);
    int*   done    = (int*)(ws + OFF_DONE);
    float* pN      = (float*)(ws + OFF_PN);
    float* pD      = (float*)(ws + OFF_PD);
    float* posvals = (float*)(ws + OFF_PV);

    k_prep<<<dim3(1024), dim3(256), 0, stream>>>(feat, tgt, fnb, rank, card,
                                                 negsum, done);
    k_main<<<dim3(TOT), dim3(256), 0, stream>>>(fnb, tgt, rank, negsum, posvals);
    k_fin<<<dim3(64), dim3(256), 0, stream>>>(negsum, rank, card, posvals,
                                              pN, pD, done, out);
}